// Round 11
// baseline (69.574 us; speedup 1.0000x reference)
//
#include <hip/hip_runtime.h>
#include <hip/hip_bf16.h>

#define B_     4
#define C_     256
#define H_     180
#define W_     180
#define NBOX   64
#define HW_    (H_ * W_)            // 32400
#define GROUPS (HW_ / 4)            // 8100 float4 groups per channel plane
#define WGRP   512                  // float4-groups per block window
#define SEGS   ((GROUPS + WGRP - 1) / WGRP)   // 16
#define KCH    8                    // channel chunks
#define NC     (C_ / KCH)           // 32 channels per chunk
#define PTILES 127                  // pixel tiles for mask/gate kernels

// workspace layout (bytes)
#define WMASK_OFF 0                                   // u8 [B_][HW_] (129600, 16-aligned)
#define PSUM_OFF  (B_ * HW_)                          // float4 [KCH][B_][GROUPS]
#define PNZ_OFF   (PSUM_OFF + KCH * B_ * GROUPS * 16) // u32 [KCH][B_][GROUPS]
#define ACC_OFF   (PNZ_OFF + KCH * B_ * GROUPS * 4)   // float sum + u32 cnt
#define WS_NEED   (ACC_OFF + 8)                       // ~5.4 MB

// ---------- K1: per-pixel box mask ----------
__global__ __launch_bounds__(256) void mfl_mask(
    const int* __restrict__ boxes,
    unsigned char* __restrict__ wmask)
{
    const int tid = threadIdx.x;
    const int bx  = blockIdx.x;
    const int b   = blockIdx.y;

    __shared__ int sbox[NBOX * 4];
    sbox[tid] = boxes[b * NBOX * 4 + tid];
    __syncthreads();

    const int hw = bx * 256 + tid;
    if (hw < HW_) {
        const int h = hw / W_, w = hw - (hw / W_) * W_;
        int msk = 0;
        #pragma unroll 8
        for (int n = 0; n < NBOX; ++n) {
            const int ltx = sbox[n * 4 + 0];
            const int lty = sbox[n * 4 + 1];
            const int rbx = sbox[n * 4 + 2];
            const int rby = sbox[n * 4 + 3];
            msk |= ((h >= lty) & (h < rby) & (w >= rbx) & (w < ltx));
        }
        wmask[b * HW_ + hw] = (unsigned char)msk;
    }
}

// ---------- K2 (hot): fully linear streaming column-sum ----------
// Grid (SEGS, KCH, B_) = 512 blocks, seg fastest (adjacent blocks tile
// adjacent 8KB windows of the same rows). Thread owns 2 float4 slots with
// register accumulators; channel loop in 4-row batches of 16 pinned loads.
// No mask gating: contiguity over fetch-savings (theory test).
__global__ __launch_bounds__(256) void mfl_stream2(
    const float4* __restrict__ x4,
    const float4* __restrict__ t4,
    float4* __restrict__ psum,
    unsigned int* __restrict__ pnz)
{
    const int tid  = threadIdx.x;
    const int lane = tid & 63;
    const int wid  = tid >> 6;
    const int seg  = blockIdx.x;
    const int k    = blockIdx.y;
    const int b    = blockIdx.z;

    const int g0 = seg * WGRP + wid * 128 + lane;   // slot 0
    const int g1 = g0 + 64;                          // slot 1
    const bool v0 = g0 < GROUPS, v1 = g1 < GROUPS;
    const int cg0 = v0 ? g0 : GROUPS - 1;            // clamp (seg 15 tail)
    const int cg1 = v1 ? g1 : GROUPS - 1;

    const size_t base = (size_t)(b * C_ + k * NC) * GROUPS;

    float4 s0 = make_float4(0.f, 0.f, 0.f, 0.f);
    float4 s1 = make_float4(0.f, 0.f, 0.f, 0.f);
    float4 z0 = make_float4(0.f, 0.f, 0.f, 0.f);
    float4 z1 = make_float4(0.f, 0.f, 0.f, 0.f);

    for (int cb = 0; cb < NC; cb += 4) {
        float4 T[8], X[8];
        #pragma unroll
        for (int j = 0; j < 4; ++j) {
            const size_t rb = base + (size_t)(cb + j) * GROUPS;
            T[2 * j]     = t4[rb + cg0];
            T[2 * j + 1] = t4[rb + cg1];
        }
        #pragma unroll
        for (int j = 0; j < 4; ++j) {
            const size_t rb = base + (size_t)(cb + j) * GROUPS;
            X[2 * j]     = x4[rb + cg0];
            X[2 * j + 1] = x4[rb + cg1];
        }
        __builtin_amdgcn_sched_barrier(0);   // all 16 loads issued before use
        #pragma unroll
        for (int j = 0; j < 8; ++j) {
            const float4 tv = T[j];
            const float4 xv = X[j];
            float4& s = (j & 1) ? s1 : s0;   // compile-time after unroll
            float4& z = (j & 1) ? z1 : z0;
            z.x += (tv.x != 0.f) ? 1.f : 0.f;
            z.y += (tv.y != 0.f) ? 1.f : 0.f;
            z.z += (tv.z != 0.f) ? 1.f : 0.f;
            z.w += (tv.w != 0.f) ? 1.f : 0.f;
            float d0 = xv.x - tv.x, d1 = xv.y - tv.y;
            float d2 = xv.z - tv.z, d3 = xv.w - tv.w;
            float m0 = 0.5f * d0 * d0, m1 = 0.5f * d1 * d1;
            float m2 = 0.5f * d2 * d2, m3 = 0.5f * d3 * d3;
            if (isnan(tv.x)) m0 = 0.f;  if (isnan(tv.y)) m1 = 0.f;
            if (isnan(tv.z)) m2 = 0.f;  if (isnan(tv.w)) m3 = 0.f;
            s.x += m0; s.y += m1; s.z += m2; s.w += m3;
        }
    }

    const size_t o = (size_t)(k * B_ + b) * GROUPS;
    if (v0) {
        psum[o + g0] = s0;
        pnz[o + g0] = (unsigned int)(z0.x > 0.f)
                    | ((unsigned int)(z0.y > 0.f) << 8)
                    | ((unsigned int)(z0.z > 0.f) << 16)
                    | ((unsigned int)(z0.w > 0.f) << 24);
    }
    if (v1) {
        psum[o + g1] = s1;
        pnz[o + g1] = (unsigned int)(z1.x > 0.f)
                    | ((unsigned int)(z1.y > 0.f) << 8)
                    | ((unsigned int)(z1.z > 0.f) << 16)
                    | ((unsigned int)(z1.w > 0.f) << 24);
    }
}

// ---------- K3: gate by mask & anynz, reduce, 2 atomics/block ----------
__global__ __launch_bounds__(256) void mfl_gate(
    const float* __restrict__ psumf,
    const unsigned char* __restrict__ pnzb,
    const unsigned char* __restrict__ wmask,
    float* __restrict__ ws_sum,
    unsigned int* __restrict__ ws_cnt)
{
    const int tid = threadIdx.x;
    const int bx  = blockIdx.x;
    const int b   = blockIdx.y;
    const int hw  = bx * 256 + tid;

    float s = 0.f;
    int   nz = 0, msk = 0;
    if (hw < HW_) {
        msk = wmask[b * HW_ + hw];
        if (msk) {
            const int g = hw >> 2, e = hw & 3;
            #pragma unroll
            for (int k = 0; k < KCH; ++k) {
                const size_t o = ((size_t)(k * B_ + b)) * GROUPS + g;
                s  += psumf[o * 4 + e];
                nz |= pnzb[o * 4 + e];
            }
        }
    }
    const bool ok = msk && nz;
    float sc = ok ? s : 0.f;
    int   cc = ok ? 1 : 0;

    #pragma unroll
    for (int off = 32; off > 0; off >>= 1) {
        sc += __shfl_down(sc, off, 64);
        cc += __shfl_down(cc, off, 64);
    }
    __shared__ float ws[4];
    __shared__ int   wc[4];
    if ((tid & 63) == 0) { ws[tid >> 6] = sc; wc[tid >> 6] = cc; }
    __syncthreads();
    if (tid == 0) {
        const float S  = ws[0] + ws[1] + ws[2] + ws[3];
        const int   Cn = wc[0] + wc[1] + wc[2] + wc[3];
        if (S != 0.f) atomicAdd(ws_sum, S);
        if (Cn != 0)  atomicAdd(ws_cnt, (unsigned int)Cn);
    }
}

__global__ void mfl_final(const float* ws_sum, const unsigned int* ws_cnt,
                          float* out)
{
    out[0] = ws_sum[0] / ((float)ws_cnt[0] * (float)C_ * (float)B_);
}

// ---------- Fallback (ws too small): round-4 fused kernel ----------
__global__ __launch_bounds__(256) void mfl_fallback(
    const float* __restrict__ x, const float* __restrict__ t,
    const int* __restrict__ boxes, float* ws_sum, unsigned int* ws_cnt)
{
    const int p = blockIdx.x * blockDim.x + threadIdx.x;
    float s = 0.0f; int cnt = 0;
    if (p < B_ * HW_) {
        const int b = p / HW_, hw = p - b * HW_;
        const int h = hw / W_, w = hw - h * W_;
        bool mask = false;
        const int* bb = boxes + b * NBOX * 4;
        for (int n = 0; n < NBOX; ++n) {
            mask |= ((h >= bb[n*4+1]) & (h < bb[n*4+3]) & (w >= bb[n*4+2]) & (w < bb[n*4+0]));
        }
        if (mask) {
            const float* xp = x + (size_t)b * C_ * HW_ + hw;
            const float* tp = t + (size_t)b * C_ * HW_ + hw;
            bool anynz = false;
            for (int c = 0; c < C_; ++c) {
                const float tv = tp[(size_t)c * HW_], xv = xp[(size_t)c * HW_];
                anynz |= (tv != 0.0f);
                const float d = xv - tv;
                float term = 0.5f * d * d;
                if (isnan(tv)) term = 0.0f;
                s += term;
            }
            if (anynz) cnt = 1; else s = 0.0f;
        }
    }
    for (int off = 32; off > 0; off >>= 1) {
        s += __shfl_down(s, off, 64); cnt += __shfl_down(cnt, off, 64);
    }
    __shared__ float ssum[4]; __shared__ int scnt[4];
    if ((threadIdx.x & 63) == 0) { ssum[threadIdx.x >> 6] = s; scnt[threadIdx.x >> 6] = cnt; }
    __syncthreads();
    if (threadIdx.x == 0) {
        const float S = ssum[0]+ssum[1]+ssum[2]+ssum[3];
        const int Cn = scnt[0]+scnt[1]+scnt[2]+scnt[3];
        if (S != 0.0f) atomicAdd(ws_sum, S);
        if (Cn != 0) atomicAdd(ws_cnt, (unsigned int)Cn);
    }
}

extern "C" void kernel_launch(void* const* d_in, const int* in_sizes, int n_in,
                              void* d_out, int out_size, void* d_ws, size_t ws_size,
                              hipStream_t stream)
{
    const float* x     = (const float*)d_in[0];
    const float* t     = (const float*)d_in[1];
    const int*   boxes = (const int*)d_in[2];
    float* out = (float*)d_out;
    char*  ws  = (char*)d_ws;

    if (ws_size < (size_t)WS_NEED) {
        float* ws_sum = (float*)ws;
        unsigned int* ws_cnt = (unsigned int*)(ws + 4);
        hipMemsetAsync(d_ws, 0, 8, stream);
        mfl_fallback<<<(B_ * HW_ + 255) / 256, 256, 0, stream>>>(x, t, boxes, ws_sum, ws_cnt);
        mfl_final<<<1, 1, 0, stream>>>(ws_sum, ws_cnt, out);
        return;
    }

    unsigned char* wmask  = (unsigned char*)(ws + WMASK_OFF);
    float4*        psum   = (float4*)(ws + PSUM_OFF);
    unsigned int*  pnz    = (unsigned int*)(ws + PNZ_OFF);
    float*         ws_sum = (float*)(ws + ACC_OFF);
    unsigned int*  ws_cnt = (unsigned int*)(ws + ACC_OFF + 4);

    hipMemsetAsync(ws + ACC_OFF, 0, 8, stream);

    dim3 gm(PTILES, B_);
    mfl_mask<<<gm, 256, 0, stream>>>(boxes, wmask);

    dim3 ga(SEGS, KCH, B_);
    mfl_stream2<<<ga, 256, 0, stream>>>((const float4*)x, (const float4*)t,
                                        psum, pnz);

    dim3 gb(PTILES, B_);
    mfl_gate<<<gb, 256, 0, stream>>>((const float*)psum,
                                     (const unsigned char*)pnz,
                                     wmask, ws_sum, ws_cnt);

    mfl_final<<<1, 1, 0, stream>>>(ws_sum, ws_cnt, out);
}

// Round 13
// 54.167 us; speedup vs baseline: 1.2844x; 1.2844x over previous
//
#include <hip/hip_runtime.h>
#include <hip/hip_bf16.h>

#define B_    4
#define C_    256
#define H_    180
#define W_    180
#define NBOX  64
#define HW_   (H_ * W_)
#define NPIX  (B_ * HW_)

// Final design (best measured: 54.2 us harness). One thread per pixel:
// box mask computed in registers from 64 boxes, then (only if masked) a
// 256-channel strided sweep accumulating 0.5*(x-t)^2 and any(t!=0);
// wave shuffle-reduce + LDS combine + one atomic pair per block.
// Six alternative structures (channel-split LDS combine, float4 ping-pong,
// copy-probe-shaped scatter, fully linear column-sum) all measured equal or
// worse: the op is bound by ~3.8 TB/s effective read service on the 253 MiB
// working set (above the chip's demonstrated 3.15 TB/s per-direction copy
// stream), not by occupancy, MLP depth, or wave-stream contiguity.
__global__ __launch_bounds__(256) void mask_feat_loss_main(
    const float* __restrict__ x,
    const float* __restrict__ t,
    const int*   __restrict__ boxes,
    float*        ws_sum,
    unsigned int* ws_cnt)
{
    const int p = blockIdx.x * blockDim.x + threadIdx.x;

    float s = 0.0f;
    int   cnt = 0;

    if (p < NPIX) {
        const int b  = p / HW_;
        const int hw = p - b * HW_;
        const int h  = hw / W_;
        const int w  = hw - h * W_;

        // Box mask: inside = (h>=lt_y) & (h<rb_y) & (w>=rb_x) & (w<lt_x)
        bool mask = false;
        const int* bb = boxes + b * NBOX * 4;
        #pragma unroll 8
        for (int n = 0; n < NBOX; ++n) {
            const int ltx = bb[n * 4 + 0];
            const int lty = bb[n * 4 + 1];
            const int rbx = bb[n * 4 + 2];
            const int rby = bb[n * 4 + 3];
            mask |= ((h >= lty) & (h < rby) & (w >= rbx) & (w < ltx));
        }

        if (mask) {
            const float* xp = x + (size_t)b * C_ * HW_ + hw;
            const float* tp = t + (size_t)b * C_ * HW_ + hw;
            bool anynz = false;
            #pragma unroll 8
            for (int c = 0; c < C_; ++c) {
                const float tv = tp[(size_t)c * HW_];
                const float xv = xp[(size_t)c * HW_];
                anynz |= (tv != 0.0f);            // NaN != 0 is true (matches ref)
                const float d = xv - tv;
                float term = 0.5f * d * d;
                if (isnan(tv)) term = 0.0f;        // t = where(isnan(t), x, t)
                s += term;
            }
            if (anynz) cnt = 1;
            else       s = 0.0f;                   // all-zero target row: weight 0
        }
    }

    // Wave (64-lane) reduction
    #pragma unroll
    for (int off = 32; off > 0; off >>= 1) {
        s   += __shfl_down(s, off, 64);
        cnt += __shfl_down(cnt, off, 64);
    }

    __shared__ float ssum[4];
    __shared__ int   scnt[4];
    const int lane = threadIdx.x & 63;
    const int wid  = threadIdx.x >> 6;
    if (lane == 0) { ssum[wid] = s; scnt[wid] = cnt; }
    __syncthreads();

    if (threadIdx.x == 0) {
        const float S  = ssum[0] + ssum[1] + ssum[2] + ssum[3];
        const int   Cn = scnt[0] + scnt[1] + scnt[2] + scnt[3];
        if (S != 0.0f) atomicAdd(ws_sum, S);
        if (Cn != 0)   atomicAdd(ws_cnt, (unsigned int)Cn);
    }
}

__global__ void mask_feat_loss_finalize(const float* ws_sum,
                                        const unsigned int* ws_cnt,
                                        float* out)
{
    const float S = ws_sum[0];
    const float n = (float)ws_cnt[0];
    // loss = S / (C * pos_norm) summed, then / B
    out[0] = S / (n * (float)C_ * (float)B_);
}

extern "C" void kernel_launch(void* const* d_in, const int* in_sizes, int n_in,
                              void* d_out, int out_size, void* d_ws, size_t ws_size,
                              hipStream_t stream)
{
    const float* x     = (const float*)d_in[0];
    const float* t     = (const float*)d_in[1];
    const int*   boxes = (const int*)d_in[2];
    float* out = (float*)d_out;

    float*        ws_sum = (float*)d_ws;
    unsigned int* ws_cnt = (unsigned int*)((char*)d_ws + sizeof(float));

    // Zero the accumulators (ws is poisoned 0xAA and never re-poisoned).
    hipMemsetAsync(d_ws, 0, 2 * sizeof(unsigned int), stream);

    const int threads = 256;
    const int blocks  = (NPIX + threads - 1) / threads;
    mask_feat_loss_main<<<blocks, threads, 0, stream>>>(x, t, boxes, ws_sum, ws_cnt);
    mask_feat_loss_finalize<<<1, 1, 0, stream>>>(ws_sum, ws_cnt, out);
}